// Round 13
// baseline (56.622 us; speedup 1.0000x reference)
//
#include <hip/hip_runtime.h>
#include <math.h>

#define BB   4      // batch
#define HH   32     // query heads
#define GG   4      // query groups (also KV heads)
#define HPG  8      // heads per group
#define DD   128    // head dim
#define NCK  128    // number of compressed keys per head
#define SEQ  8192   // key/value sequence length
#define NSEL 16     // selected blocks
#define BLK  64     // block size
#define NPROD 256   // producer blocks

// Single kernel, 1024 blocks x 256 threads, all co-resident (4/CU).
// Blocks 0..255: produce e=exp(score) + per-(bh,half) psum (ordinary stores),
//   then __threadfence + one device-scope release atomicAdd on a counter.
// All blocks: spin (relaxed polls, one acquire at the end) until counter==256,
//   then R12's select+gather: p = sum_j e_j/s_j, rank, copy 16 KB half-block.
__global__ __launch_bounds__(256, 4) void fused_nsa_kernel(
    const float* __restrict__ query,
    const float* __restrict__ ck,
    const float* __restrict__ keys,
    const float* __restrict__ values,
    float* __restrict__ e_ws,       // 4*32*128 floats
    float* __restrict__ ps_ws,      // 256 floats
    unsigned int* __restrict__ ctr, // 1 uint, memset to 0 each call
    float* __restrict__ out)
{
    const int bid = blockIdx.x;      // 0..1023
    const int t   = threadIdx.x;     // 0..255

    __shared__ float q_sh[DD];
    __shared__ float wred[4];
    __shared__ float pm[NCK];
    __shared__ int   sel_sh;

    // ---------------- producer: gemv + exp + psum ----------------
    if (bid < NPROD) {
        const int bh   = bid >> 1;             // 0..127
        const int half = bid & 1;
        const int r    = half * 64 + (t >> 2); // row 0..127
        const int sub  = t & 3;                // quarter of the row
        const int w    = t >> 6;               // wave 0..3

        if (t < DD) q_sh[t] = query[(size_t)bh * DD + t];
        __syncthreads();

        const float4* c4 = (const float4*)(ck + ((size_t)bh * NCK + r) * DD) + sub;
        const float4* q4 = ((const float4*)q_sh) + sub;
        float s = 0.0f;
        #pragma unroll
        for (int i = 0; i < 8; ++i) {
            float4 a = q4[i * 4];
            float4 c = c4[i * 4];              // 4 lanes -> contiguous 64 B
            s += a.x * c.x + a.y * c.y + a.z * c.z + a.w * c.w;
        }
        s += __shfl_xor(s, 1);
        s += __shfl_xor(s, 2);                 // identical on the row's 4 lanes

        const float e = expf(s * 0.08838834764831845f);  // no-max: scores ~N(0,1)
        if (sub == 0) e_ws[(size_t)bh * NCK + r] = e;

        // wave butterfly: 16 rows x4 dup -> bsum = 4 * sum(16 rows)
        float bsum = e;
        #pragma unroll
        for (int off = 1; off < 64; off <<= 1) bsum += __shfl_xor(bsum, off);
        if ((t & 63) == 0) wred[w] = bsum * 0.25f;       // exact /4
        __syncthreads();
        if (t == 0)
            ps_ws[bh * 2 + half] = (wred[0] + wred[1]) + (wred[2] + wred[3]);

        __threadfence();                       // each thread fences its own stores
        __syncthreads();
        if (t == 0)
            __hip_atomic_fetch_add(ctr, 1u, __ATOMIC_RELEASE, __HIP_MEMORY_SCOPE_AGENT);
    }

    // ---------------- wait for all producers ----------------
    if (t == 0) {
        while (__hip_atomic_load(ctr, __ATOMIC_RELAXED, __HIP_MEMORY_SCOPE_AGENT) != NPROD)
            __builtin_amdgcn_s_sleep(2);
        (void)__hip_atomic_load(ctr, __ATOMIC_ACQUIRE, __HIP_MEMORY_SCOPE_AGENT); // one inv
    }
    __syncthreads();

    // ---------------- consumer: select + gather (R12 verbatim) ----------------
    const int q2   = bid & 3;
    const int isV  = q2 >> 1;
    const int half = q2 & 1;
    const int s    = (bid >> 2) & 15;          // rank this block copies
    const int bg   = bid >> 6;                 // 0..15
    const int b    = bg >> 2;
    const int g    = bg & 3;

    if (t < NCK) {
        const int base = b * HH + g * HPG;
        float p = 0.0f;
        #pragma unroll
        for (int j = 0; j < HPG; ++j) {
            const float ej = e_ws[(size_t)(base + j) * NCK + t];
            const float sj = ps_ws[(base + j) * 2] + ps_ws[(base + j) * 2 + 1];
            p += ej / sj;
        }
        pm[t] = p;                             // mean scaling dropped: rank-invariant
    }
    __syncthreads();

    if (t < NCK) {
        const float mv = pm[t];
        int rank = 0;
        for (int i = 0; i < NCK; ++i) {
            const float vi = pm[i];            // uniform index -> LDS broadcast
            if (vi > mv || (vi == mv && i < t)) ++rank;
        }
        if (rank == s) sel_sh = t;             // exactly one thread matches
    }
    __syncthreads();
    const int sel = sel_sh;

    const size_t src  = ((size_t)bg * SEQ + (size_t)sel * BLK + half * 32) * DD;
    const size_t dst  = ((size_t)bg * (NSEL * BLK) + (size_t)s * BLK + half * 32) * DD;
    const size_t VOFF = (size_t)BB * GG * NSEL * BLK * DD;

    const float4* sp = (const float4*)((isV ? values : keys) + src);
    float4*       dp = (float4*)(out + (isV ? VOFF : 0) + dst);

    #pragma unroll
    for (int i = 0; i < 4; ++i) dp[i * 256 + t] = sp[i * 256 + t];
}

extern "C" void kernel_launch(void* const* d_in, const int* in_sizes, int n_in,
                              void* d_out, int out_size, void* d_ws, size_t ws_size,
                              hipStream_t stream) {
    const float* query  = (const float*)d_in[0];   // (4,32,1,128)
    const float* ck     = (const float*)d_in[1];   // (4,32,128,128)
    const float* keys   = (const float*)d_in[2];   // (4,4,8192,128)
    const float* values = (const float*)d_in[3];   // (4,4,8192,128)
    float* out = (float*)d_out;

    const size_t OFF_PS  = (size_t)BB * HH * NCK * sizeof(float);   // 65536
    const size_t OFF_CTR = OFF_PS + (size_t)BB * HH * 2 * sizeof(float); // 66560

    float*        e_ws  = (float*)d_ws;
    float*        ps_ws = (float*)((char*)d_ws + OFF_PS);
    unsigned int* ctr   = (unsigned int*)((char*)d_ws + OFF_CTR);

    hipMemsetAsync(ctr, 0, sizeof(unsigned int), stream);   // deterministic reset
    fused_nsa_kernel<<<BB * GG * NSEL * 4, 256, 0, stream>>>(query, ck, keys, values,
                                                             e_ws, ps_ws, ctr, out);
}

// Round 14
// 19.239 us; speedup vs baseline: 2.9431x; 2.9431x over previous
//
#include <hip/hip_runtime.h>
#include <math.h>

#define BB   4      // batch
#define HH   32     // query heads
#define GG   4      // query groups (also KV heads)
#define HPG  8      // heads per group
#define DD   128    // head dim
#define NCK  128    // number of compressed keys per head
#define SEQ  8192   // key/value sequence length
#define NSEL 16     // selected blocks
#define BLK  64     // block size

// Kernel 1: one block per (b,h) = 128 blocks x 1024 threads (128 rows x 8 lanes).
// GEMV + no-max softmax fully in-block; writes NORMALIZED probs.
__global__ __launch_bounds__(1024, 1) void head_softmax_kernel(const float* __restrict__ query,
                                                               const float* __restrict__ ck,
                                                               float* __restrict__ probs_out) {
    const int bh  = blockIdx.x;          // 0..127
    const int t   = threadIdx.x;         // 0..1023
    const int r   = t >> 3;              // row 0..127
    const int sub = t & 7;               // eighth of the row
    const int w   = t >> 6;              // wave 0..15

    __shared__ float q_sh[DD];
    __shared__ float wred[16];

    if (t < DD) q_sh[t] = query[(size_t)bh * DD + t];
    __syncthreads();

    const float4* c4 = (const float4*)(ck + ((size_t)bh * NCK + r) * DD) + sub;
    const float4* q4 = ((const float4*)q_sh) + sub;
    float s = 0.0f;
    #pragma unroll
    for (int i = 0; i < 4; ++i) {
        float4 a = q4[i * 8];
        float4 c = c4[i * 8];            // 8 lanes -> contiguous 128 B line
        s += a.x * c.x + a.y * c.y + a.z * c.z + a.w * c.w;
    }
    s += __shfl_xor(s, 1);
    s += __shfl_xor(s, 2);
    s += __shfl_xor(s, 4);               // identical on the row's 8 lanes

    const float e = expf(s * 0.08838834764831845f);   // no-max: scores ~N(0,1)

    // wave butterfly: 8 rows x8 dup -> bsum = 8 * sum(8 rows)
    float bsum = e;
    #pragma unroll
    for (int off = 1; off < 64; off <<= 1) bsum += __shfl_xor(bsum, off);
    if ((t & 63) == 0) wred[w] = bsum * 0.125f;       // exact /8
    __syncthreads();

    float S = 0.0f;
    #pragma unroll
    for (int i = 0; i < 16; ++i) S += wred[i];        // fixed order: deterministic

    if (sub == 0) probs_out[(size_t)bh * NCK + r] = e / S;
}

// Kernel 2: one block per (bg, s, half, K-or-V) = 1024 blocks x 256 threads.
// Prefix: 8 loads + 7 adds -> pm; float4 rank loop; then 16 KB copy.
__global__ __launch_bounds__(256, 1) void select_gather_kernel(const float* __restrict__ probs,
                                                               const float* __restrict__ keys,
                                                               const float* __restrict__ values,
                                                               float* __restrict__ out) {
    const int bid  = blockIdx.x;         // 0..1023
    const int q2   = bid & 3;
    const int isV  = q2 >> 1;
    const int half = q2 & 1;
    const int s    = (bid >> 2) & 15;    // rank this block copies
    const int bg   = bid >> 6;           // 0..15
    const int b    = bg >> 2;
    const int g    = bg & 3;
    const int t    = threadIdx.x;        // 0..255

    __shared__ float pm[NCK];
    __shared__ int   sel_sh;

    if (t < NCK) {
        const int base = b * HH + g * HPG;
        float p = 0.0f;
        #pragma unroll
        for (int j = 0; j < HPG; ++j)
            p += probs[(size_t)(base + j) * NCK + t];
        pm[t] = p;                        // mean scaling dropped: rank-invariant
    }
    __syncthreads();

    // rank of row t (stable descending = lax.top_k order), float4 LDS reads
    if (t < NCK) {
        const float mv = pm[t];
        const float4* pm4 = (const float4*)pm;
        int rank = 0;
        #pragma unroll 8
        for (int i = 0; i < NCK / 4; ++i) {
            const float4 v = pm4[i];
            const int i0 = 4 * i;
            rank += (v.x > mv || (v.x == mv && (i0 + 0) < t));
            rank += (v.y > mv || (v.y == mv && (i0 + 1) < t));
            rank += (v.z > mv || (v.z == mv && (i0 + 2) < t));
            rank += (v.w > mv || (v.w == mv && (i0 + 3) < t));
        }
        if (rank == s) sel_sh = t;        // exactly one thread matches
    }
    __syncthreads();
    const int sel = sel_sh;

    // copy a 32x128 half-block: 1024 float4, 256 threads -> 4 each
    const size_t src  = ((size_t)bg * SEQ + (size_t)sel * BLK + half * 32) * DD;
    const size_t dst  = ((size_t)bg * (NSEL * BLK) + (size_t)s * BLK + half * 32) * DD;
    const size_t VOFF = (size_t)BB * GG * NSEL * BLK * DD;

    const float4* sp = (const float4*)((isV ? values : keys) + src);
    float4*       dp = (float4*)(out + (isV ? VOFF : 0) + dst);

    #pragma unroll
    for (int i = 0; i < 4; ++i) dp[i * 256 + t] = sp[i * 256 + t];
}

extern "C" void kernel_launch(void* const* d_in, const int* in_sizes, int n_in,
                              void* d_out, int out_size, void* d_ws, size_t ws_size,
                              hipStream_t stream) {
    const float* query  = (const float*)d_in[0];   // (4,32,1,128)
    const float* ck     = (const float*)d_in[1];   // (4,32,128,128)
    const float* keys   = (const float*)d_in[2];   // (4,4,8192,128)
    const float* values = (const float*)d_in[3];   // (4,4,8192,128)
    float* out = (float*)d_out;

    float* probs = (float*)d_ws;                   // 64 KB

    head_softmax_kernel<<<BB * HH, 1024, 0, stream>>>(query, ck, probs);
    select_gather_kernel<<<BB * GG * NSEL * 4, 256, 0, stream>>>(probs, keys, values, out);
}

// Round 16
// 17.886 us; speedup vs baseline: 3.1657x; 1.0756x over previous
//
#include <hip/hip_runtime.h>
#include <math.h>

#define BB   4      // batch
#define HH   32     // query heads
#define GG   4      // query groups (also KV heads)
#define HPG  8      // heads per group
#define DD   128    // head dim
#define NCK  128    // number of compressed keys per head
#define SEQ  8192   // key/value sequence length
#define NSEL 16     // selected blocks
#define BLK  64     // block size

typedef float vf4 __attribute__((ext_vector_type(4)));   // native vec for nt-store

// Kernel 1 (R12-proven): GEMV + exp + deterministic partial exp-sums.
// One block per (b,h,half): 64 rows x 8 lanes/row, coalesced.
__global__ __launch_bounds__(512, 1) void gemv_exp_kernel(const float* __restrict__ query,
                                                          const float* __restrict__ ck,
                                                          float* __restrict__ e_out,
                                                          float* __restrict__ psum_out) {
    const int blk  = blockIdx.x;         // 0..255
    const int bh   = blk >> 1;           // 0..127
    const int half = blk & 1;
    const int t    = threadIdx.x;        // 0..511
    const int r    = (t >> 3) + half * 64;
    const int sub  = t & 7;
    const int w    = t >> 6;             // wave 0..7

    __shared__ float q_sh[DD];
    __shared__ float wred[8];

    if (t < DD) q_sh[t] = query[(size_t)bh * DD + t];
    __syncthreads();

    const float4* c4 = (const float4*)(ck + ((size_t)bh * NCK + r) * DD) + sub;
    const float4* q4 = ((const float4*)q_sh) + sub;
    float s = 0.0f;
    #pragma unroll
    for (int i = 0; i < 4; ++i) {
        float4 a = q4[i * 8];
        float4 c = c4[i * 8];            // 8 lanes -> contiguous 128 B line
        s += a.x * c.x + a.y * c.y + a.z * c.z + a.w * c.w;
    }
    s += __shfl_xor(s, 1);
    s += __shfl_xor(s, 2);
    s += __shfl_xor(s, 4);               // identical on the row's 8 lanes

    const float e = expf(s * 0.08838834764831845f);   // no-max: scores ~N(0,1)
    if (sub == 0) e_out[(size_t)bh * NCK + r] = e;

    // wave butterfly: 8 rows x8 dup -> bsum = 8 * sum(8 rows)
    float bsum = e;
    #pragma unroll
    for (int off = 1; off < 64; off <<= 1) bsum += __shfl_xor(bsum, off);
    if ((t & 63) == 0) wred[w] = bsum * 0.125f;       // exact /8
    __syncthreads();

    if (t == 0) {
        float p = 0.0f;
        #pragma unroll
        for (int i = 0; i < 8; ++i) p += wred[i];     // fixed order: deterministic
        psum_out[bh * 2 + half] = p;
    }
}

// Kernel 2: one block per (bg, s, half, K-or-V) = 1024 blocks x 256 threads.
// Prefix: 8 e-loads + LDS-hoisted reciprocals + FMA -> pm; float4 rank; NT-store copy.
__global__ __launch_bounds__(256, 1) void select_gather_kernel(const float* __restrict__ e_in,
                                                               const float* __restrict__ psum,
                                                               const float* __restrict__ keys,
                                                               const float* __restrict__ values,
                                                               float* __restrict__ out) {
    const int bid  = blockIdx.x;         // 0..1023
    const int q2   = bid & 3;
    const int isV  = q2 >> 1;
    const int half = q2 & 1;
    const int s    = (bid >> 2) & 15;    // rank this block copies
    const int bg   = bid >> 6;           // 0..15
    const int b    = bg >> 2;
    const int g    = bg & 3;
    const int t    = threadIdx.x;        // 0..255

    __shared__ float inv_s[HPG];
    __shared__ float pm[NCK];
    __shared__ int   sel_sh;

    const int base = b * HH + g * HPG;

    float ej[HPG];
    if (t < NCK) {
        #pragma unroll
        for (int j = 0; j < HPG; ++j)
            ej[j] = e_in[(size_t)(base + j) * NCK + t];   // 8 coalesced loads
    }
    if (t < HPG)                                           // 8 divides per block total
        inv_s[t] = 1.0f / (psum[(base + t) * 2] + psum[(base + t) * 2 + 1]);
    __syncthreads();

    if (t < NCK) {
        float p = 0.0f;
        #pragma unroll
        for (int j = 0; j < HPG; ++j) p = fmaf(ej[j], inv_s[j], p);
        pm[t] = p;                        // mean scaling dropped: rank-invariant
    }
    __syncthreads();

    // rank of row t (stable descending = lax.top_k order), float4 LDS broadcasts
    if (t < NCK) {
        const float mv = pm[t];
        const float4* pm4 = (const float4*)pm;
        int rank = 0;
        #pragma unroll 8
        for (int i = 0; i < NCK / 4; ++i) {
            const float4 v = pm4[i];
            const int i0 = 4 * i;
            rank += (v.x > mv || (v.x == mv && (i0 + 0) < t));
            rank += (v.y > mv || (v.y == mv && (i0 + 1) < t));
            rank += (v.z > mv || (v.z == mv && (i0 + 2) < t));
            rank += (v.w > mv || (v.w == mv && (i0 + 3) < t));
        }
        if (rank == s) sel_sh = t;        // exactly one thread matches
    }
    __syncthreads();
    const int sel = sel_sh;

    // copy a 32x128 half-block: 1024 float4, 256 threads -> 4 each; NT stores
    const size_t src  = ((size_t)bg * SEQ + (size_t)sel * BLK + half * 32) * DD;
    const size_t dst  = ((size_t)bg * (NSEL * BLK) + (size_t)s * BLK + half * 32) * DD;
    const size_t VOFF = (size_t)BB * GG * NSEL * BLK * DD;

    const vf4* sp = (const vf4*)((isV ? values : keys) + src);
    vf4*       dp = (vf4*)(out + (isV ? VOFF : 0) + dst);

    #pragma unroll
    for (int i = 0; i < 4; ++i) {
        const vf4 v = sp[i * 256 + t];
        __builtin_nontemporal_store(v, &dp[i * 256 + t]);
    }
}

extern "C" void kernel_launch(void* const* d_in, const int* in_sizes, int n_in,
                              void* d_out, int out_size, void* d_ws, size_t ws_size,
                              hipStream_t stream) {
    const float* query  = (const float*)d_in[0];   // (4,32,1,128)
    const float* ck     = (const float*)d_in[1];   // (4,32,128,128)
    const float* keys   = (const float*)d_in[2];   // (4,4,8192,128)
    const float* values = (const float*)d_in[3];   // (4,4,8192,128)
    float* out = (float*)d_out;

    float* e_ws  = (float*)d_ws;                                        // 64 KB
    float* ps_ws = (float*)((char*)d_ws + (size_t)BB * HH * NCK * sizeof(float)); // 1 KB

    gemv_exp_kernel<<<BB * HH * 2, 512, 0, stream>>>(query, ck, e_ws, ps_ws);
    select_gather_kernel<<<BB * GG * NSEL * 4, 256, 0, stream>>>(e_ws, ps_ws, keys, values, out);
}